// Round 1
// baseline (415.096 us; speedup 1.0000x reference)
//
#include <hip/hip_runtime.h>
#include <hip/hip_cooperative_groups.h>
#include <cstdint>
#include <cstddef>

// ---------------------------------------------------------------------------
// FeatureEncoder — spike-time encoding.
//   x: (64, 1, 1000, 128) fp32.  Per-batch min/max over (F,Bd) = 128000 elems.
//   norm = (8*(x-min))/(max-min)   (EXACT ref arithmetic, IEEE fp32 div)
//   out[..., j] = (norm > perm[j]) ? 1 : 0, perm = jax.random.permutation(key(1), 8)
//   out: (64, 1, 1000, 128, 8) fp32, time-axis contiguous.
//
// R3 -> R4: rocprof top-5 is ALL harness poison-fills (1.049 GB @ ~163 us each);
// our 3 kernels sum to only ~60 us of the 285. Remaining controllable cost is
// our own dispatch count + init kernel + atomic funnel. Fuse init+minmax+encode
// into ONE cooperative kernel (1024 blocks, 4/CU co-resident, grid.sync between
// reduce and encode). Per-block partials via agent-scope atomics (XCD-safe);
// no init pass needed since every partial slot is rewritten each iteration
// before the grid sync. Block->slice mapping identical across phases so the
// encode-phase input re-read hits the same CU's L1/L2.
// Encode store pattern unchanged from R2/R3: lane-contiguous f32x4 NT stores
// (1 KB per wave instruction) — already at write roofline structurally.
// ---------------------------------------------------------------------------

namespace cg = cooperative_groups;

typedef float f32x4 __attribute__((ext_vector_type(4)));

// ===== compile-time jax.random.permutation(jax.random.key(1), 8) =====
// Verified exact in R1 (absmax 0): partitionable split + 32-bit fold bits,
// stable sort of arange by bits.
struct TF2 { uint32_t a, b; };

constexpr uint32_t rotl32(uint32_t x, int d) { return (x << d) | (x >> (32 - d)); }

constexpr TF2 threefry2x32(uint32_t k0, uint32_t k1, uint32_t x0, uint32_t x1) {
  const uint32_t ks2 = k0 ^ k1 ^ 0x1BD11BDAu;
  const int R0[4] = {13, 15, 26, 6};
  const int R1[4] = {17, 29, 16, 24};
  x0 += k0; x1 += k1;
  for (int i = 0; i < 4; ++i) { x0 += x1; x1 = rotl32(x1, R0[i]); x1 ^= x0; }
  x0 += k1; x1 += ks2 + 1u;
  for (int i = 0; i < 4; ++i) { x0 += x1; x1 = rotl32(x1, R1[i]); x1 ^= x0; }
  x0 += ks2; x1 += k0 + 2u;
  for (int i = 0; i < 4; ++i) { x0 += x1; x1 = rotl32(x1, R0[i]); x1 ^= x0; }
  x0 += k0; x1 += k1 + 3u;
  for (int i = 0; i < 4; ++i) { x0 += x1; x1 = rotl32(x1, R1[i]); x1 ^= x0; }
  x0 += k1; x1 += ks2 + 4u;
  for (int i = 0; i < 4; ++i) { x0 += x1; x1 = rotl32(x1, R0[i]); x1 ^= x0; }
  x0 += ks2; x1 += k0 + 5u;
  return TF2{x0, x1};
}

struct Perm { int p[8]; };

constexpr Perm compute_perm() {
  TF2 s = threefry2x32(0u, 1u, 0u, 1u);      // foldlike split -> subkey
  uint32_t sk0 = s.a, sk1 = s.b;
  uint32_t bits[8] = {};
  for (int i = 0; i < 8; ++i) {
    TF2 r = threefry2x32(sk0, sk1, 0u, (uint32_t)i);
    bits[i] = r.a ^ r.b;
  }
  Perm perm = {{0, 1, 2, 3, 4, 5, 6, 7}};
  for (int i = 1; i < 8; ++i) {
    uint32_t kb = bits[i]; int kv = perm.p[i];
    int j = i - 1;
    while (j >= 0 && bits[j] > kb) { bits[j + 1] = bits[j]; perm.p[j + 1] = perm.p[j]; --j; }
    bits[j + 1] = kb; perm.p[j + 1] = kv;
  }
  return perm;
}

constexpr Perm PERM = compute_perm();

// ===== geometry =====
static constexpr int B = 64;
static constexpr int PER_BATCH_F4 = 32000;                 // 128000 floats / 4
static constexpr int BLOCKS_PER_BATCH = 16;
static constexpr int GRID_BLOCKS = B * BLOCKS_PER_BATCH;   // 1024 (4/CU — co-resident)
static constexpr int MM_F4_PER_BLOCK = PER_BATCH_F4 / BLOCKS_PER_BATCH;  // 2000
static constexpr int OUT4_PER_BLOCK = 16000;               // 256000 out-f4/batch / 16

__global__ __launch_bounds__(256, 4) void fused_encoder(const float* __restrict__ in,
                                                        f32x4* __restrict__ out,
                                                        float* __restrict__ part) {
  const int blk = blockIdx.x;
  const int batch = blk >> 4;
  const int sub = blk & 15;

  // ---- phase 1: per-block min/max over this block's 32 KB input slice ----
  const float4* bp = (const float4*)in + (size_t)batch * PER_BATCH_F4;
  float mn = INFINITY, mx = -INFINITY;
  const int end = (sub + 1) * MM_F4_PER_BLOCK;
  for (int i = sub * MM_F4_PER_BLOCK + threadIdx.x; i < end; i += 256) {
    float4 v = bp[i];
    mn = fminf(mn, fminf(fminf(v.x, v.y), fminf(v.z, v.w)));
    mx = fmaxf(mx, fmaxf(fmaxf(v.x, v.y), fmaxf(v.z, v.w)));
  }
  #pragma unroll
  for (int off = 32; off > 0; off >>= 1) {
    mn = fminf(mn, __shfl_down(mn, off));
    mx = fmaxf(mx, __shfl_down(mx, off));
  }
  __shared__ float smn[4], smx[4];
  const int wave = threadIdx.x >> 6, lane = threadIdx.x & 63;
  if (lane == 0) { smn[wave] = mn; smx[wave] = mx; }
  __syncthreads();
  if (threadIdx.x == 0) {
    mn = fminf(fminf(smn[0], smn[1]), fminf(smn[2], smn[3]));
    mx = fmaxf(fmaxf(smx[0], smx[1]), fmaxf(smx[2], smx[3]));
    // agent-scope atomic stores: visible across XCDs (per-XCD L2 non-coherent).
    // No init pass needed: both slots unconditionally rewritten every iteration
    // before any read (ordering via grid.sync below).
    __hip_atomic_store(&part[2 * blk],     mn, __ATOMIC_RELAXED, __HIP_MEMORY_SCOPE_AGENT);
    __hip_atomic_store(&part[2 * blk + 1], mx, __ATOMIC_RELAXED, __HIP_MEMORY_SCOPE_AGENT);
  }

  cg::this_grid().sync();

  // ---- phase 2: reduce this batch's 16 partial pairs, then encode ----
  __shared__ float s_red[2];
  if (threadIdx.x < 16) {
    float pmn = __hip_atomic_load(&part[2 * (batch * 16 + threadIdx.x)],
                                  __ATOMIC_RELAXED, __HIP_MEMORY_SCOPE_AGENT);
    float pmx = __hip_atomic_load(&part[2 * (batch * 16 + threadIdx.x) + 1],
                                  __ATOMIC_RELAXED, __HIP_MEMORY_SCOPE_AGENT);
    #pragma unroll
    for (int off = 8; off > 0; off >>= 1) {
      pmn = fminf(pmn, __shfl_down(pmn, off));
      pmx = fmaxf(pmx, __shfl_down(pmx, off));
    }
    if (threadIdx.x == 0) { s_red[0] = pmn; s_red[1] = pmx; }
  }
  __syncthreads();
  const float bmn = s_red[0];
  const float rng = s_red[1] - bmn;

  // thread parity fixed across all stores (stride 256 even, block base even):
  // even out4 -> time slots 0..3, odd out4 -> time slots 4..7.
  const int p = (threadIdx.x & 1) * 4;
  const float th0 = (float)PERM.p[p + 0];
  const float th1 = (float)PERM.p[p + 1];
  const float th2 = (float)PERM.p[p + 2];
  const float th3 = (float)PERM.p[p + 3];

  // Same slice this block reduced in phase 1 -> input re-read is L1/L2-hot.
  const int out4_base = blk * OUT4_PER_BLOCK;
  #pragma unroll 4
  for (int i = threadIdx.x; i < OUT4_PER_BLOCK; i += 256) {
    const int o4 = out4_base + i;
    const float x = in[o4 >> 1];                 // 2 lanes share 1 elem (coalesced)
    // EXACT ref arithmetic: (8*(x-mn)) / rng, IEEE fp32 division.
    const float n = (8.0f * (x - bmn)) / rng;
    f32x4 o;
    o.x = n > th0 ? 1.0f : 0.0f;
    o.y = n > th1 ? 1.0f : 0.0f;
    o.z = n > th2 ? 1.0f : 0.0f;
    o.w = n > th3 ? 1.0f : 0.0f;
    __builtin_nontemporal_store(o, &out[o4]);    // lane-contiguous, no reuse
  }
}

extern "C" void kernel_launch(void* const* d_in, const int* in_sizes, int n_in,
                              void* d_out, int out_size, void* d_ws, size_t ws_size,
                              hipStream_t stream) {
  const float* in = (const float*)d_in[0];
  f32x4* out = (f32x4*)d_out;
  float* part = (float*)d_ws;                    // 2048 floats = 8 KB of workspace

  void* args[3] = {(void*)&in, (void*)&out, (void*)&part};
  hipLaunchCooperativeKernel((const void*)fused_encoder, dim3(GRID_BLOCKS), dim3(256),
                             args, 0, stream);
}

// Round 2
// 280.467 us; speedup vs baseline: 1.4800x; 1.4800x over previous
//
#include <hip/hip_runtime.h>
#include <cstdint>
#include <cstddef>

// ---------------------------------------------------------------------------
// FeatureEncoder — spike-time encoding.
//   x: (64, 1, 1000, 128) fp32.  Per-batch min/max over (F,Bd) = 128000 elems.
//   norm = (8*(x-min))/(max-min)   (EXACT ref arithmetic, IEEE fp32 div)
//   out[..., j] = (norm > perm[j]) ? 1 : 0, perm = jax.random.permutation(key(1), 8)
//   out: (64, 1, 1000, 128, 8) fp32, time-axis contiguous.
//
// R4 -> R5 (post-mortem of cooperative fusion): fused kernel alone was 185 us
// (1.55 TB/s, 42% occupancy from forced 4-blocks/CU co-residency + grid.sync
// fence) vs ~57 us for the split pipeline. dur_us = ~228 us fixed harness
// overhead + our kernel time (R0/R1 arithmetic consistent). REVERT to split
// structure; recover the small overheads instead:
//   - drop init_keys kernel + atomic funnel: minmax plain-stores per-block
//     partials (dispatch-boundary release/acquire makes them visible across
//     XCDs); each encode block shuffle-reduces its batch's 32 partials (~0.5us
//     total, L2-hot).
//   - minmax grid 1024 -> 2048 blocks (8/CU): full-occupancy read ramp.
//   - partial-reduce shuffles run with the FULL wave active (identities in
//     lanes >= 32) — R1's divergent-shfl read inactive-lane registers (UB).
// Encode store pattern unchanged (lane-contiguous f32x4 NT stores, 1 KB/instr,
// structurally at write roofline).
// ---------------------------------------------------------------------------

typedef float f32x4 __attribute__((ext_vector_type(4)));

// ===== compile-time jax.random.permutation(jax.random.key(1), 8) =====
// Verified exact in R1 (absmax 0): partitionable split + 32-bit fold bits,
// stable sort of arange by bits.
struct TF2 { uint32_t a, b; };

constexpr uint32_t rotl32(uint32_t x, int d) { return (x << d) | (x >> (32 - d)); }

constexpr TF2 threefry2x32(uint32_t k0, uint32_t k1, uint32_t x0, uint32_t x1) {
  const uint32_t ks2 = k0 ^ k1 ^ 0x1BD11BDAu;
  const int R0[4] = {13, 15, 26, 6};
  const int R1[4] = {17, 29, 16, 24};
  x0 += k0; x1 += k1;
  for (int i = 0; i < 4; ++i) { x0 += x1; x1 = rotl32(x1, R0[i]); x1 ^= x0; }
  x0 += k1; x1 += ks2 + 1u;
  for (int i = 0; i < 4; ++i) { x0 += x1; x1 = rotl32(x1, R1[i]); x1 ^= x0; }
  x0 += ks2; x1 += k0 + 2u;
  for (int i = 0; i < 4; ++i) { x0 += x1; x1 = rotl32(x1, R0[i]); x1 ^= x0; }
  x0 += k0; x1 += k1 + 3u;
  for (int i = 0; i < 4; ++i) { x0 += x1; x1 = rotl32(x1, R1[i]); x1 ^= x0; }
  x0 += k1; x1 += ks2 + 4u;
  for (int i = 0; i < 4; ++i) { x0 += x1; x1 = rotl32(x1, R0[i]); x1 ^= x0; }
  x0 += ks2; x1 += k0 + 5u;
  return TF2{x0, x1};
}

struct Perm { int p[8]; };

constexpr Perm compute_perm() {
  TF2 s = threefry2x32(0u, 1u, 0u, 1u);      // foldlike split -> subkey
  uint32_t sk0 = s.a, sk1 = s.b;
  uint32_t bits[8] = {};
  for (int i = 0; i < 8; ++i) {
    TF2 r = threefry2x32(sk0, sk1, 0u, (uint32_t)i);
    bits[i] = r.a ^ r.b;
  }
  Perm perm = {{0, 1, 2, 3, 4, 5, 6, 7}};
  for (int i = 1; i < 8; ++i) {
    uint32_t kb = bits[i]; int kv = perm.p[i];
    int j = i - 1;
    while (j >= 0 && bits[j] > kb) { bits[j + 1] = bits[j]; perm.p[j + 1] = perm.p[j]; --j; }
    bits[j + 1] = kb; perm.p[j + 1] = kv;
  }
  return perm;
}

constexpr Perm PERM = compute_perm();

// ===== geometry =====
static constexpr int B = 64;
static constexpr int PER_BATCH_F4 = 32000;                 // 128000 floats / 4
static constexpr int MM_BLOCKS_PER_BATCH = 32;             // 2048 blocks = 8/CU
static constexpr int MM_F4_PER_BLOCK = PER_BATCH_F4 / MM_BLOCKS_PER_BATCH;  // 1000

// encode: out float4 count = 64*128000*8/4 = 16,384,000.
// Each block: 256 threads x 8 stores = 2048 out-float4 (32 KB).
static constexpr int ENC_OUT4_PER_BLOCK = 2048;
static constexpr int ENC_BLOCKS = 16384000 / ENC_OUT4_PER_BLOCK;  // 8000
static constexpr int ENC_BLOCKS_PER_BATCH = 125;                  // exact: 256000/2048

__global__ __launch_bounds__(256) void minmax_kernel(const float4* __restrict__ in,
                                                     float2* __restrict__ part) {
  const int batch = blockIdx.x >> 5;
  const int sub = blockIdx.x & 31;
  const float4* bp = in + (size_t)batch * PER_BATCH_F4;
  float mn = INFINITY, mx = -INFINITY;
  const int end = (sub + 1) * MM_F4_PER_BLOCK;
  for (int i = sub * MM_F4_PER_BLOCK + threadIdx.x; i < end; i += 256) {
    float4 v = bp[i];
    mn = fminf(mn, fminf(fminf(v.x, v.y), fminf(v.z, v.w)));
    mx = fmaxf(mx, fmaxf(fmaxf(v.x, v.y), fmaxf(v.z, v.w)));
  }
  #pragma unroll
  for (int off = 32; off > 0; off >>= 1) {
    mn = fminf(mn, __shfl_down(mn, off));
    mx = fmaxf(mx, __shfl_down(mx, off));
  }
  __shared__ float smn[4], smx[4];
  const int wave = threadIdx.x >> 6, lane = threadIdx.x & 63;
  if (lane == 0) { smn[wave] = mn; smx[wave] = mx; }
  __syncthreads();
  if (threadIdx.x == 0) {
    mn = fminf(fminf(smn[0], smn[1]), fminf(smn[2], smn[3]));
    mx = fmaxf(fmaxf(smx[0], smx[1]), fmaxf(smx[2], smx[3]));
    // plain store: dispatch-boundary release/acquire orders this before the
    // encode kernel's loads, across all XCDs. Distinct slot per block: no race.
    part[blockIdx.x] = make_float2(mn, mx);
  }
}

__global__ __launch_bounds__(256) void encode_kernel(const float* __restrict__ in,
                                                     f32x4* __restrict__ out,
                                                     const float2* __restrict__ part) {
  const int batch = blockIdx.x / ENC_BLOCKS_PER_BATCH;   // 125 blocks/batch exact

  // ---- reduce this batch's 32 per-block partials (L2-hot, 256 B) ----
  __shared__ float s_red[2];
  if (threadIdx.x < 64) {                       // full wave active: shfl defined
    float pmn = INFINITY, pmx = -INFINITY;
    if (threadIdx.x < MM_BLOCKS_PER_BATCH) {
      float2 v = part[batch * MM_BLOCKS_PER_BATCH + threadIdx.x];
      pmn = v.x; pmx = v.y;
    }
    #pragma unroll
    for (int off = 16; off > 0; off >>= 1) {
      pmn = fminf(pmn, __shfl_down(pmn, off));
      pmx = fmaxf(pmx, __shfl_down(pmx, off));
    }
    if (threadIdx.x == 0) { s_red[0] = pmn; s_red[1] = pmx; }
  }
  __syncthreads();
  const float mn = s_red[0];
  const float rng = s_red[1] - mn;

  // thread parity fixed across all 8 stores (stride 256 is even):
  // even out4 -> time slots 0..3, odd out4 -> time slots 4..7.
  const int p = (threadIdx.x & 1) * 4;
  const float th0 = (float)PERM.p[p + 0];
  const float th1 = (float)PERM.p[p + 1];
  const float th2 = (float)PERM.p[p + 2];
  const float th3 = (float)PERM.p[p + 3];

  const int out4_base = blockIdx.x * ENC_OUT4_PER_BLOCK + threadIdx.x;
  #pragma unroll
  for (int k = 0; k < 8; ++k) {
    const int o4 = out4_base + k * 256;          // lane-contiguous per instruction
    const float x = in[o4 >> 1];                 // 2 lanes share 1 elem (coalesced)
    // EXACT ref arithmetic: (8*(x-mn)) / rng, IEEE fp32 division.
    const float n = (8.0f * (x - mn)) / rng;
    f32x4 o;
    o.x = n > th0 ? 1.0f : 0.0f;
    o.y = n > th1 ? 1.0f : 0.0f;
    o.z = n > th2 ? 1.0f : 0.0f;
    o.w = n > th3 ? 1.0f : 0.0f;
    __builtin_nontemporal_store(o, &out[o4]);    // no reuse; skip L2 pollution
  }
}

extern "C" void kernel_launch(void* const* d_in, const int* in_sizes, int n_in,
                              void* d_out, int out_size, void* d_ws, size_t ws_size,
                              hipStream_t stream) {
  const float* in = (const float*)d_in[0];
  f32x4* out = (f32x4*)d_out;
  float2* part = (float2*)d_ws;                  // 2048 float2 = 16 KB workspace

  hipLaunchKernelGGL(minmax_kernel, dim3(B * MM_BLOCKS_PER_BATCH), dim3(256), 0, stream,
                     (const float4*)in, part);
  hipLaunchKernelGGL(encode_kernel, dim3(ENC_BLOCKS), dim3(256), 0, stream,
                     in, out, part);
}